// Round 8
// baseline (397.100 us; speedup 1.0000x reference)
//
#include <hip/hip_runtime.h>
#include <hip/hip_bf16.h>
#include <stdint.h>

// TernaryLinear: out = scale * (x_bf16 @ wq_bf16^T), scale = mean|W|+1e-8
// M=8192, K=2048, N=8192. fp32 in/out.
//
// GEMM: 256x256 tile, BK=64, 8 waves (2x4). R5 sync skeleton (2 barriers +
// counted vm(4) per K-tile) + fully phase-ahead reads.
// Quadrants: Q0(a03,b01) Q2(a47,b01) Q1(a03,b23) Q3(a47,b23).
//   ph1: RD_A47(CB) [->Q2]      | stage B(T+1)h0 -> OB.B | MFMA Q0
//   ph2: RD_B23(CB) [->Q1]      | stage B(T+1)h1         | MFMA Q2 | BAR
//   ph3: stage A(T+2)h0,h1 -> CB.A                       | MFMA Q1 | vm(4) BAR
//   ph4: RD_A03(OB), RD_B01(OB) [->next Q0]              | MFMA Q3
// Reads never feed same-phase MFMA (a03/b01: 1 phase + a barrier ahead; a47: 1
// phase; b23: 1 phase; Q3 operands 2-3 phases old). Register liveness (single
// sets): a03 used ph1,ph3, overwritten ph4' of SAME tile? no - ph4 reads OB's
// a03 for tile T+1 after Q1@ph3 done (program order) OK; b01 used ph1,ph2,
// overwritten ph4 (Q3 doesn't use b01) OK; a47 used ph2,ph4, overwritten next
// ph1 OK; b23 used ph3,ph4, overwritten next ph2 OK.
// WAR: B(T+1)->OB.B@ph1: OB.B's last ds_reads (b23 of T-1 @T-1ph2) retired
// before T-1 ph2-end BAR (2 barriers ago) OK. A(T+2)->CB.A@ph3: CB.A ds_reads
// (a03@T-1ph4, a47@Tph1) retire before their consuming MFMAs (<= ph2), all
// waves pass ph2-end BAR OK.
// RAW: vm(4)@ph3-end: outstanding = B(T+1)4 + A(T+2)4; leaves A(T+2) => forces
// B(T+1) and (older) A(T+1); BAR => ph4's OB reads safe. Never vm(0) in loop.
// vmcnt ledger (per-wave instrs, 2 per STAGE): stages/tile = B:2+A:2 STAGE = 8
// loads; steady outstanding at ph3-end = 8, vm(4) leaves 4. Tail: tile 30
// stages only B(31) -> vm(0) at its ph3-end (outstanding=4, tail-only drain).

typedef __attribute__((ext_vector_type(8))) short   s16x8;
typedef __attribute__((ext_vector_type(4))) float   f32x4;

#define K_DIM   2048
#define K2      4096        // row stride bytes (bf16)
#define N_DIM   8192
#define N4      4194304     // 8192*2048/4

// ---------------- scale reduction ----------------
__global__ void k_abs_part(const float4* __restrict__ w4, float* __restrict__ part) {
    int tid = blockIdx.x * 256 + threadIdx.x;
    float s = 0.f;
    for (int i = tid; i < N4; i += gridDim.x * 256) {
        float4 v = w4[i];
        s += fabsf(v.x) + fabsf(v.y) + fabsf(v.z) + fabsf(v.w);
    }
    for (int off = 32; off > 0; off >>= 1) s += __shfl_down(s, off, 64);
    __shared__ float tmp[4];
    int lane = threadIdx.x & 63, wid = threadIdx.x >> 6;
    if (lane == 0) tmp[wid] = s;
    __syncthreads();
    if (threadIdx.x == 0) part[blockIdx.x] = tmp[0] + tmp[1] + tmp[2] + tmp[3];
}

__global__ void k_abs_final(const float* __restrict__ part, float* __restrict__ scale) {
    float s = part[threadIdx.x] + part[threadIdx.x + 256] +
              part[threadIdx.x + 512] + part[threadIdx.x + 768];
    for (int off = 32; off > 0; off >>= 1) s += __shfl_down(s, off, 64);
    __shared__ float tmp[4];
    int lane = threadIdx.x & 63, wid = threadIdx.x >> 6;
    if (lane == 0) tmp[wid] = s;
    __syncthreads();
    if (threadIdx.x == 0) scale[0] = (tmp[0] + tmp[1] + tmp[2] + tmp[3]) / 16777216.0f + 1e-8f;
}

// ---------------- fused W-quant + X-convert ----------------
__device__ __forceinline__ uint32_t f2b(float f) {
    uint32_t u = __builtin_bit_cast(uint32_t, f);
    return (u + 0x7FFFu + ((u >> 16) & 1u)) >> 16;  // RNE
}

__global__ void k_prep(const float4* __restrict__ w4, const float4* __restrict__ x4,
                       const float* __restrict__ scale_p,
                       uint2* __restrict__ wq, uint2* __restrict__ xb) {
    int tid = (blockIdx.x & 2047) * 256 + threadIdx.x;
    if (blockIdx.x < 2048) {
        const float sc = *scale_p;
        for (int i = tid; i < N4; i += 2048 * 256) {
            float4 v = w4[i];
            float q0 = rintf(v.x / sc), q1 = rintf(v.y / sc);
            float q2 = rintf(v.z / sc), q3 = rintf(v.w / sc);
            uint32_t b0 = (q0 == 0.f) ? 0u : (q0 > 0.f ? 0x3F80u : 0xBF80u);
            uint32_t b1 = (q1 == 0.f) ? 0u : (q1 > 0.f ? 0x3F80u : 0xBF80u);
            uint32_t b2 = (q2 == 0.f) ? 0u : (q2 > 0.f ? 0x3F80u : 0xBF80u);
            uint32_t b3 = (q3 == 0.f) ? 0u : (q3 > 0.f ? 0x3F80u : 0xBF80u);
            uint2 o; o.x = b0 | (b1 << 16); o.y = b2 | (b3 << 16);
            wq[i] = o;
        }
    } else {
        for (int i = tid; i < N4; i += 2048 * 256) {
            float4 v = x4[i];
            uint2 o;
            o.x = f2b(v.x) | (f2b(v.y) << 16);
            o.y = f2b(v.z) | (f2b(v.w) << 16);
            xb[i] = o;
        }
    }
}

// ---------------- GEMM ----------------
__device__ __forceinline__ void mfma16(f32x4& c, s16x8 a, s16x8 b) {
    asm("v_mfma_f32_16x16x32_bf16 %0, %1, %2, %0" : "+v"(c) : "v"(a), "v"(b));
}
__device__ __forceinline__ void load_lds16(const void* g, void* l) {
    __builtin_amdgcn_global_load_lds(
        (const __attribute__((address_space(1))) uint32_t*)g,
        (__attribute__((address_space(3))) uint32_t*)l, 16, 0, 0);
}

#define SCHED0 __builtin_amdgcn_sched_barrier(0)
#define SBAR do { SCHED0; __builtin_amdgcn_s_barrier(); SCHED0; } while (0)
#define WAIT_VM(N) do { asm volatile("s_waitcnt vmcnt(" #N ")" ::: "memory"); SCHED0; } while (0)

// LDS byte map (128 KiB): buf0.A=0, buf0.B=32768, buf1.A=65536, buf1.B=98304
#define C0 0
#define C1 65536

__global__ __launch_bounds__(512, 2) void k_gemm(
    const unsigned short* __restrict__ Xb,
    const unsigned short* __restrict__ Wb,
    const float* __restrict__ scale_p,
    float* __restrict__ out)
{
    extern __shared__ uint8_t smem[];
    const int tid  = threadIdx.x;
    const int lane = tid & 63;
    const int wid  = tid >> 6;
    const int wr   = wid >> 2;          // 0..1
    const int wc   = wid & 3;           // 0..3

    // XCD-aware bijective swizzle (1024 % 8 == 0)
    const int bid = blockIdx.x;
    const int swz = (bid & 7) * 128 + (bid >> 3);
    const int tileRow = swz >> 5;       // 0..31
    const int tileCol = swz & 31;

    const uint8_t* gA = (const uint8_t*)Xb + (size_t)tileRow * 256 * K2;
    const uint8_t* gB = (const uint8_t*)Wb + (size_t)tileCol * 256 * K2;

    // staging: thread t covers row srow and srow+64 of a 128-row x 64-K half-region.
    // physical LDS slot c of row r holds global col-slot (c ^ (r&7))  (XOR swizzle).
    const int srow = tid >> 3, sslot = tid & 7;
    const size_t srcOff = (size_t)srow * K2 + (size_t)((sslot ^ (srow & 7)) * 16);
    const uint8_t* gAs = gA + srcOff;
    const uint8_t* gBs = gB + srcOff;
    const int dstOff = tid * 16;

    // LDS read bases (byte offsets); frag m adds m*2048 (16 rows * 128B)
    const int rA = wr * 128 + (lane & 15);
    const int rB = wc * 64  + (lane & 15);
    const int h  = lane >> 4;
    const int pA0 = rA * 128 + (((h    ) ^ (rA & 7)) * 16);
    const int pA1 = rA * 128 + (((4 + h) ^ (rA & 7)) * 16);
    const int pB0 = rB * 128 + (((h    ) ^ (rB & 7)) * 16);
    const int pB1 = rB * 128 + (((4 + h) ^ (rB & 7)) * 16);

    s16x8 a[8][2], b[4][2];
    f32x4 acc[8][4];
    #pragma unroll
    for (int m = 0; m < 8; ++m)
        #pragma unroll
        for (int n = 0; n < 4; ++n) acc[m][n] = (f32x4){0.f, 0.f, 0.f, 0.f};

#define LD8(OFF) (*(const s16x8*)(smem + (OFF)))
#define STAGE(LBASE, GP, BOFF) do { \
    load_lds16((GP) + (BOFF),          smem + (LBASE) + dstOff); \
    load_lds16((GP) + (BOFF) + 262144, smem + (LBASE) + 8192 + dstOff); \
    SCHED0; } while (0)

#define RD_A03(AB) do { _Pragma("unroll") for (int m = 0; m < 4; ++m) { \
    a[m][0] = LD8((AB) + pA0 + m * 2048); a[m][1] = LD8((AB) + pA1 + m * 2048); } } while (0)
#define RD_A47(AB) do { _Pragma("unroll") for (int m = 4; m < 8; ++m) { \
    a[m][0] = LD8((AB) + pA0 + m * 2048); a[m][1] = LD8((AB) + pA1 + m * 2048); } } while (0)
#define RD_B01(AB) do { _Pragma("unroll") for (int n = 0; n < 2; ++n) { \
    b[n][0] = LD8((AB) + 32768 + pB0 + n * 2048); b[n][1] = LD8((AB) + 32768 + pB1 + n * 2048); } } while (0)
#define RD_B23(AB) do { _Pragma("unroll") for (int n = 2; n < 4; ++n) { \
    b[n][0] = LD8((AB) + 32768 + pB0 + n * 2048); b[n][1] = LD8((AB) + 32768 + pB1 + n * 2048); } } while (0)

#define MFMA_Q(MLO, NLO) do { \
    __builtin_amdgcn_s_setprio(1); \
    _Pragma("unroll") for (int kk = 0; kk < 2; ++kk) \
        _Pragma("unroll") for (int m = 0; m < 4; ++m) \
            _Pragma("unroll") for (int n = 0; n < 2; ++n) \
                mfma16(acc[(MLO) + m][(NLO) + n], a[(MLO) + m][kk], b[(NLO) + n][kk]); \
    __builtin_amdgcn_s_setprio(0); \
    SCHED0; } while (0)

// One K-tile t (on CB). KB1 = byte k-offset of tile t+1 (B stage -> OB.B),
// KB2 = offset of tile t+2 (A stage -> CB.A). SB/SA = stage enables, NEN =
// next-tile read enable, VM = vmcnt arg at ph3-end (4 steady, 0 tail).
#define TILE(CB, OB, KB1, KB2, SB, SA, NEN, VM) do { \
    /* ph1 */ \
    RD_A47(CB); \
    if (SB) STAGE((OB) + 32768, gBs, (KB1)); \
    MFMA_Q(0, 0); \
    /* ph2 */ \
    RD_B23(CB); \
    if (SB) STAGE((OB) + 49152, gBs, 524288 + (KB1)); \
    MFMA_Q(4, 0); \
    SBAR; \
    /* ph3 */ \
    if (SA) { STAGE((CB), gAs, (KB2)); STAGE((CB) + 16384, gAs, 524288 + (KB2)); } \
    MFMA_Q(0, 2); \
    WAIT_VM(VM); SBAR; \
    /* ph4 */ \
    if (NEN) { RD_A03(OB); RD_B01(OB); } \
    MFMA_Q(4, 2); \
} while (0)

    // prologue: stage A(0),B(0)->C0 and A(1)->C1.A; vm(4) leaves A(1) in flight;
    // preload a03(0), b01(0) (the "T-1 ph4" reads for tile 0).
    STAGE(C0,         gAs, 0);   STAGE(C0 + 16384, gAs, 524288);
    STAGE(C0 + 32768, gBs, 0);   STAGE(C0 + 49152, gBs, 524288);
    STAGE(C1,         gAs, 128); STAGE(C1 + 16384, gAs, 524288 + 128);
    WAIT_VM(4);
    SBAR;
    RD_A03(C0);
    RD_B01(C0);
    SCHED0;

    #pragma unroll 1
    for (int i = 0; i < 15; ++i) {
        const int t0 = 2 * i, t1 = 2 * i + 1;
        TILE(C0, C1, (t0 + 1) * 128, (t0 + 2) * 128, 1, 1, 1, 4);
        TILE(C1, C0, (t1 + 1) * 128, (t1 + 2) * 128, 1, 1, 1, 4);
    }
    // tail: tile 30 stages only B(31) (vm(0) drains it); tile 31 stages nothing
    TILE(C0, C1, 31 * 128, 0, 1, 0, 1, 0);
    TILE(C1, C0, 0, 0, 0, 0, 0, 0);

    // epilogue: C[row][col], col=lane&15, row=(lane>>4)*4+j (verified mapping)
    const float sc = *scale_p;
    const int orow0 = tileRow * 256 + wr * 128 + ((lane >> 4) << 2);
    const int ocol0 = tileCol * 256 + wc * 64 + (lane & 15);
    #pragma unroll
    for (int m = 0; m < 8; ++m)
        #pragma unroll
        for (int n = 0; n < 4; ++n)
            #pragma unroll
            for (int j = 0; j < 4; ++j)
                out[(size_t)(orow0 + m * 16 + j) * N_DIM + (ocol0 + n * 16)] = acc[m][n][j] * sc;

#undef LD8
#undef STAGE
#undef RD_A03
#undef RD_A47
#undef RD_B01
#undef RD_B23
#undef MFMA_Q
#undef TILE
}

// ---------------- launch ----------------
extern "C" void kernel_launch(void* const* d_in, const int* in_sizes, int n_in,
                              void* d_out, int out_size, void* d_ws, size_t ws_size,
                              hipStream_t stream) {
    const float* x = (const float*)d_in[0];
    const float* w = (const float*)d_in[1];
    float* out = (float*)d_out;
    uint8_t* ws = (uint8_t*)d_ws;

    float* part  = (float*)ws;                       // 1024 floats
    float* scale = (float*)(ws + 4096);              // 1 float
    unsigned short* Xb = (unsigned short*)(ws + 8192);
    unsigned short* Wb = (unsigned short*)(ws + 8192 + 33554432ull);

    (void)hipFuncSetAttribute((const void*)k_gemm,
                              hipFuncAttributeMaxDynamicSharedMemorySize, 131072);

    hipLaunchKernelGGL(k_abs_part, dim3(1024), dim3(256), 0, stream, (const float4*)w, part);
    hipLaunchKernelGGL(k_abs_final, dim3(1), dim3(256), 0, stream, part, scale);
    hipLaunchKernelGGL(k_prep, dim3(4096), dim3(256), 0, stream,
                       (const float4*)w, (const float4*)x, scale, (uint2*)Wb, (uint2*)Xb);
    hipLaunchKernelGGL(k_gemm, dim3(1024), dim3(512), 131072, stream, Xb, Wb, scale, out);
}

// Round 9
// 379.423 us; speedup vs baseline: 1.0466x; 1.0466x over previous
//
#include <hip/hip_runtime.h>
#include <hip/hip_bf16.h>
#include <stdint.h>

// TernaryLinear: out = scale * (x_bf16 @ wq_bf16^T), scale = mean|W|+1e-8
// M=8192, K=2048, N=8192. fp32 in/out.
//
// GEMM: 256x256, BK=64, 8 waves (2x4). m201-faithful 8-phase iteration
// (2 K-tiles: T=2i on buf0, T+1 on buf1). Phase = {reads(next-phase ops);
// 1 half-tile stage; BAR; lgkm0; setprio1; 16 MFMA; setprio0; [vm]; BAR}.
//
//  ph  reads             stage          MFMA      vm
//  1   a47(T)   [8,b0]   B(T+1)h0->b1   Q00(T)    -
//  2   b23(T)   [4,b0]   B(T+1)h1       Q40(T)    -
//  3   -                 A(T+2)h0->b0   Q02(T)    vm(2)
//  4   a03,b01(T+1)[12]  A(T+2)h1       Q42(T)    -
//  5   a47(T+1) [8,b1]   B(T+2)h0->b0   Q00(T+1)  -
//  6   b23(T+1) [4,b1]   B(T+2)h1       Q40(T+1)  -
//  7   -                 A(T+3)h0->b1   Q02(T+1)  vm(2)
//  8   a03,b01(T+2)[12]  A(T+3)h1       Q42(T+1)  -
//
// Reads feed the NEXT phase's MFMA (lgkm0 after BAR drains them during barrier
// convergence). Register clobber audit (single sets): a47 rd ph1/ph5, last use
// ph4/ph8; b23 rd ph2/ph6, last use ph4/ph8; b01 rd ph4/ph8, last use ph2/ph6
// (next tile); a03 rd ph4/ph8, last use ph3/ph7 (next tile) - all clean.
// WAR (stage >= 1 barrier after region's last ds_read retires): b1.B last rd
// b23(T-1)@prev-ph6 -> dead prev-ph7-end -> stage ph1 OK. b0.A last rd a47(T)@ph1
// -> dead ph2-end -> stage ph3 OK. b0.B last rd b23(T)@ph2 -> dead ph3-end ->
// stage ph5 OK. b1.A last rd a47(T+1)@ph5 -> dead ph6-end -> stage ph7 OK.
// RAW (counted vm, never 0 in loop): ph3-end queue = [A(T+1)h0,h1(prev7,8),
// B(T+1)h0,h1(ph1,2), A(T+2)h0(ph3)] = 10 loads -> vm(2) forces A(T+1)+B(T+1)
// (exactly what ph4/5/6 read), leaves A(T+2)h0. ph7-end queue = [A(T+2)h0,h1,
// B(T+2)h0,h1, A(T+3)h0] = 10 -> vm(2) forces A(T+2)+B(T+2) (ph8 reads), leaves
// A(T+3)h0. Prologue stages A(0),B(0),A(1), vm(4) leaves A(1) = steady entry.

typedef __attribute__((ext_vector_type(8))) short   s16x8;
typedef __attribute__((ext_vector_type(4))) float   f32x4;

#define K_DIM   2048
#define K2      4096        // row stride bytes (bf16)
#define N_DIM   8192
#define N4      4194304     // 8192*2048/4

// ---------------- scale reduction ----------------
__global__ void k_abs_part(const float4* __restrict__ w4, float* __restrict__ part) {
    int tid = blockIdx.x * 256 + threadIdx.x;
    float s = 0.f;
    for (int i = tid; i < N4; i += gridDim.x * 256) {
        float4 v = w4[i];
        s += fabsf(v.x) + fabsf(v.y) + fabsf(v.z) + fabsf(v.w);
    }
    for (int off = 32; off > 0; off >>= 1) s += __shfl_down(s, off, 64);
    __shared__ float tmp[4];
    int lane = threadIdx.x & 63, wid = threadIdx.x >> 6;
    if (lane == 0) tmp[wid] = s;
    __syncthreads();
    if (threadIdx.x == 0) part[blockIdx.x] = tmp[0] + tmp[1] + tmp[2] + tmp[3];
}

__global__ void k_abs_final(const float* __restrict__ part, float* __restrict__ scale) {
    float s = part[threadIdx.x] + part[threadIdx.x + 256] +
              part[threadIdx.x + 512] + part[threadIdx.x + 768];
    for (int off = 32; off > 0; off >>= 1) s += __shfl_down(s, off, 64);
    __shared__ float tmp[4];
    int lane = threadIdx.x & 63, wid = threadIdx.x >> 6;
    if (lane == 0) tmp[wid] = s;
    __syncthreads();
    if (threadIdx.x == 0) scale[0] = (tmp[0] + tmp[1] + tmp[2] + tmp[3]) / 16777216.0f + 1e-8f;
}

// ---------------- fused W-quant + X-convert ----------------
__device__ __forceinline__ uint32_t f2b(float f) {
    uint32_t u = __builtin_bit_cast(uint32_t, f);
    return (u + 0x7FFFu + ((u >> 16) & 1u)) >> 16;  // RNE
}

__global__ void k_prep(const float4* __restrict__ w4, const float4* __restrict__ x4,
                       const float* __restrict__ scale_p,
                       uint2* __restrict__ wq, uint2* __restrict__ xb) {
    int tid = (blockIdx.x & 2047) * 256 + threadIdx.x;
    if (blockIdx.x < 2048) {
        const float sc = *scale_p;
        for (int i = tid; i < N4; i += 2048 * 256) {
            float4 v = w4[i];
            float q0 = rintf(v.x / sc), q1 = rintf(v.y / sc);
            float q2 = rintf(v.z / sc), q3 = rintf(v.w / sc);
            uint32_t b0 = (q0 == 0.f) ? 0u : (q0 > 0.f ? 0x3F80u : 0xBF80u);
            uint32_t b1 = (q1 == 0.f) ? 0u : (q1 > 0.f ? 0x3F80u : 0xBF80u);
            uint32_t b2 = (q2 == 0.f) ? 0u : (q2 > 0.f ? 0x3F80u : 0xBF80u);
            uint32_t b3 = (q3 == 0.f) ? 0u : (q3 > 0.f ? 0x3F80u : 0xBF80u);
            uint2 o; o.x = b0 | (b1 << 16); o.y = b2 | (b3 << 16);
            wq[i] = o;
        }
    } else {
        for (int i = tid; i < N4; i += 2048 * 256) {
            float4 v = x4[i];
            uint2 o;
            o.x = f2b(v.x) | (f2b(v.y) << 16);
            o.y = f2b(v.z) | (f2b(v.w) << 16);
            xb[i] = o;
        }
    }
}

// ---------------- GEMM ----------------
__device__ __forceinline__ void mfma16(f32x4& c, s16x8 a, s16x8 b) {
    asm("v_mfma_f32_16x16x32_bf16 %0, %1, %2, %0" : "+v"(c) : "v"(a), "v"(b));
}
__device__ __forceinline__ void load_lds16(const void* g, void* l) {
    __builtin_amdgcn_global_load_lds(
        (const __attribute__((address_space(1))) uint32_t*)g,
        (__attribute__((address_space(3))) uint32_t*)l, 16, 0, 0);
}

#define SCHED0 __builtin_amdgcn_sched_barrier(0)
#define SBAR do { SCHED0; __builtin_amdgcn_s_barrier(); SCHED0; } while (0)
#define LGKM0 do { asm volatile("s_waitcnt lgkmcnt(0)" ::: "memory"); SCHED0; } while (0)
#define WAIT_VM(N) do { asm volatile("s_waitcnt vmcnt(" #N ")" ::: "memory"); SCHED0; } while (0)

// LDS byte map (128 KiB): buf0.A=0, buf0.B=32768, buf1.A=65536, buf1.B=98304
#define C0 0
#define C1 65536

__global__ __launch_bounds__(512, 2) void k_gemm(
    const unsigned short* __restrict__ Xb,
    const unsigned short* __restrict__ Wb,
    const float* __restrict__ scale_p,
    float* __restrict__ out)
{
    extern __shared__ uint8_t smem[];
    const int tid  = threadIdx.x;
    const int lane = tid & 63;
    const int wid  = tid >> 6;
    const int wr   = wid >> 2;          // 0..1
    const int wc   = wid & 3;           // 0..3

    // XCD-aware bijective swizzle (1024 % 8 == 0)
    const int bid = blockIdx.x;
    const int swz = (bid & 7) * 128 + (bid >> 3);
    const int tileRow = swz >> 5;       // 0..31
    const int tileCol = swz & 31;

    const uint8_t* gA = (const uint8_t*)Xb + (size_t)tileRow * 256 * K2;
    const uint8_t* gB = (const uint8_t*)Wb + (size_t)tileCol * 256 * K2;

    // staging: one STAGE = one 128-row x 64-K half-tile (16KB) via 2 gload_lds.
    // physical LDS slot c of row r holds global col-slot (c ^ (r&7)) (XOR swz).
    const int srow = tid >> 3, sslot = tid & 7;
    const size_t srcOff = (size_t)srow * K2 + (size_t)((sslot ^ (srow & 7)) * 16);
    const uint8_t* gAs = gA + srcOff;
    const uint8_t* gBs = gB + srcOff;
    const int dstOff = tid * 16;

    // LDS read bases (byte offsets); frag m adds m*2048 (16 rows * 128B)
    const int rA = wr * 128 + (lane & 15);
    const int rB = wc * 64  + (lane & 15);
    const int h  = lane >> 4;
    const int pA0 = rA * 128 + (((h    ) ^ (rA & 7)) * 16);
    const int pA1 = rA * 128 + (((4 + h) ^ (rA & 7)) * 16);
    const int pB0 = rB * 128 + (((h    ) ^ (rB & 7)) * 16);
    const int pB1 = rB * 128 + (((4 + h) ^ (rB & 7)) * 16);

    s16x8 a[8][2], b[4][2];
    f32x4 acc[8][4];
    #pragma unroll
    for (int m = 0; m < 8; ++m)
        #pragma unroll
        for (int n = 0; n < 4; ++n) acc[m][n] = (f32x4){0.f, 0.f, 0.f, 0.f};

#define LD8(OFF) (*(const s16x8*)(smem + (OFF)))
#define STAGE(LBASE, GP, BOFF) do { \
    load_lds16((GP) + (BOFF),          smem + (LBASE) + dstOff); \
    load_lds16((GP) + (BOFF) + 262144, smem + (LBASE) + 8192 + dstOff); \
    SCHED0; } while (0)

#define RD_A03(AB) do { _Pragma("unroll") for (int m = 0; m < 4; ++m) { \
    a[m][0] = LD8((AB) + pA0 + m * 2048); a[m][1] = LD8((AB) + pA1 + m * 2048); } } while (0)
#define RD_A47(AB) do { _Pragma("unroll") for (int m = 4; m < 8; ++m) { \
    a[m][0] = LD8((AB) + pA0 + m * 2048); a[m][1] = LD8((AB) + pA1 + m * 2048); } } while (0)
#define RD_B01(AB) do { _Pragma("unroll") for (int n = 0; n < 2; ++n) { \
    b[n][0] = LD8((AB) + 32768 + pB0 + n * 2048); b[n][1] = LD8((AB) + 32768 + pB1 + n * 2048); } } while (0)
#define RD_B23(AB) do { _Pragma("unroll") for (int n = 2; n < 4; ++n) { \
    b[n][0] = LD8((AB) + 32768 + pB0 + n * 2048); b[n][1] = LD8((AB) + 32768 + pB1 + n * 2048); } } while (0)

#define MFMA_Q(MLO, NLO) do { \
    __builtin_amdgcn_s_setprio(1); \
    _Pragma("unroll") for (int kk = 0; kk < 2; ++kk) \
        _Pragma("unroll") for (int m = 0; m < 4; ++m) \
            _Pragma("unroll") for (int n = 0; n < 2; ++n) \
                mfma16(acc[(MLO) + m][(NLO) + n], a[(MLO) + m][kk], b[(NLO) + n][kk]); \
    __builtin_amdgcn_s_setprio(0); \
    SCHED0; } while (0)

    // prologue: A(0),B(0)->buf0, A(1)->buf1.A; vm(4) leaves A(1) in flight
    // (primes the steady queue); preload a03(0),b01(0) ("prev ph8" reads).
    STAGE(C0,         gAs, 0);   STAGE(C0 + 16384, gAs, 524288);
    STAGE(C0 + 32768, gBs, 0);   STAGE(C0 + 49152, gBs, 524288);
    STAGE(C1,         gAs, 128); STAGE(C1 + 16384, gAs, 524288 + 128);
    WAIT_VM(4);
    SBAR;
    RD_A03(C0); RD_B01(C0);
    SCHED0;

    #pragma unroll 1
    for (int i = 0; i < 15; ++i) {
        const int kb1 = (2 * i + 1) * 128;   // T+1
        const int kb2 = kb1 + 128;           // T+2
        const int kb3 = kb1 + 256;           // T+3
        // ph1
        RD_A47(C0); STAGE(C1 + 32768, gBs, kb1);
        SBAR; LGKM0; MFMA_Q(0, 0); SBAR;
        // ph2
        RD_B23(C0); STAGE(C1 + 49152, gBs, 524288 + kb1);
        SBAR; LGKM0; MFMA_Q(4, 0); SBAR;
        // ph3
        STAGE(C0, gAs, kb2);
        SBAR; LGKM0; MFMA_Q(0, 2); WAIT_VM(2); SBAR;
        // ph4
        RD_A03(C1); RD_B01(C1); STAGE(C0 + 16384, gAs, 524288 + kb2);
        SBAR; LGKM0; MFMA_Q(4, 2); SBAR;
        // ph5
        RD_A47(C1); STAGE(C0 + 32768, gBs, kb2);
        SBAR; LGKM0; MFMA_Q(0, 0); SBAR;
        // ph6
        RD_B23(C1); STAGE(C0 + 49152, gBs, 524288 + kb2);
        SBAR; LGKM0; MFMA_Q(4, 0); SBAR;
        // ph7
        STAGE(C1, gAs, kb3);
        SBAR; LGKM0; MFMA_Q(0, 2); WAIT_VM(2); SBAR;
        // ph8
        RD_A03(C0); RD_B01(C0); STAGE(C1 + 16384, gAs, 524288 + kb3);
        SBAR; LGKM0; MFMA_Q(4, 2); SBAR;
    }

    // peeled i=15 (T=30,31): stage only B(31) at ph1/ph2; vm(0) at ph3 drains
    // the remaining queue [A(31),B(31)] (tail-only full drain).
    {
        const int kb1 = 31 * 128;
        RD_A47(C0); STAGE(C1 + 32768, gBs, kb1);
        SBAR; LGKM0; MFMA_Q(0, 0); SBAR;
        RD_B23(C0); STAGE(C1 + 49152, gBs, 524288 + kb1);
        SBAR; LGKM0; MFMA_Q(4, 0); SBAR;
        SBAR; LGKM0; MFMA_Q(0, 2); WAIT_VM(0); SBAR;
        RD_A03(C1); RD_B01(C1);
        SBAR; LGKM0; MFMA_Q(4, 2); SBAR;
        RD_A47(C1);
        SBAR; LGKM0; MFMA_Q(0, 0); SBAR;
        RD_B23(C1);
        SBAR; LGKM0; MFMA_Q(4, 0); SBAR;
        SBAR; LGKM0; MFMA_Q(0, 2); SBAR;
        LGKM0; MFMA_Q(4, 2);
    }

    // epilogue: C[row][col], col=lane&15, row=(lane>>4)*4+j (verified mapping)
    const float sc = *scale_p;
    const int orow0 = tileRow * 256 + wr * 128 + ((lane >> 4) << 2);
    const int ocol0 = tileCol * 256 + wc * 64 + (lane & 15);
    #pragma unroll
    for (int m = 0; m < 8; ++m)
        #pragma unroll
        for (int n = 0; n < 4; ++n)
            #pragma unroll
            for (int j = 0; j < 4; ++j)
                out[(size_t)(orow0 + m * 16 + j) * N_DIM + (ocol0 + n * 16)] = acc[m][n][j] * sc;

#undef LD8
#undef STAGE
#undef RD_A03
#undef RD_A47
#undef RD_B01
#undef RD_B23
#undef MFMA_Q
}

// ---------------- launch ----------------
extern "C" void kernel_launch(void* const* d_in, const int* in_sizes, int n_in,
                              void* d_out, int out_size, void* d_ws, size_t ws_size,
                              hipStream_t stream) {
    const float* x = (const float*)d_in[0];
    const float* w = (const float*)d_in[1];
    float* out = (float*)d_out;
    uint8_t* ws = (uint8_t*)d_ws;

    float* part  = (float*)ws;                       // 1024 floats
    float* scale = (float*)(ws + 4096);              // 1 float
    unsigned short* Xb = (unsigned short*)(ws + 8192);
    unsigned short* Wb = (unsigned short*)(ws + 8192 + 33554432ull);

    (void)hipFuncSetAttribute((const void*)k_gemm,
                              hipFuncAttributeMaxDynamicSharedMemorySize, 131072);

    hipLaunchKernelGGL(k_abs_part, dim3(1024), dim3(256), 0, stream, (const float4*)w, part);
    hipLaunchKernelGGL(k_abs_final, dim3(1), dim3(256), 0, stream, part, scale);
    hipLaunchKernelGGL(k_prep, dim3(4096), dim3(256), 0, stream,
                       (const float4*)w, (const float4*)x, scale, (uint2*)Wb, (uint2*)Xb);
    hipLaunchKernelGGL(k_gemm, dim3(1024), dim3(512), 131072, stream, Xb, Wb, scale, out);
}

// Round 11
// 277.808 us; speedup vs baseline: 1.4294x; 1.3658x over previous
//
#include <hip/hip_runtime.h>
#include <hip/hip_bf16.h>
#include <stdint.h>

// TernaryLinear: out = scale * (x_bf16 @ wq_bf16^T), scale = mean|W|+1e-8
// M=8192, K=2048, N=8192. fp32 in/out.
//
// GEMM: byte-for-byte the 263us R5 kernel; ONLY the block->tile mapping is new.
// Minimal-barrier pipeline, 2 barriers + counted vm(4) per K-tile:
//   ph1: STAGE B(T+1)h0 | rd a03,b01 (12) | MFMA Q00
//   ph2: STAGE B(T+1)h1 | rd a47 (8)      | MFMA Q40 | BAR (buf.A dead)
//   ph3: STAGE A(T+2)h0 | rd b23 (4)      | MFMA Q02
//   ph4: STAGE A(T+2)h1 |                 | MFMA Q42 | vm(4) BAR (T+1 landed)
// (R10's NaN was a quadrant reorder that consumed b23 before its read; the
// mapping itself is a bijective index remap, correctness-neutral.)
//
// 4x8 supertiled XCD mapping: xcd owns 4 tileRows; concurrent 32 blocks/XCD =
// 4 rows x 8 cols -> working set 4 A-panels + 8 B-panels = 24MB (vs old 1x32:
// 64MB of B, L2-thrash, FETCH=549MB). B reused 4x concurrently.

typedef __attribute__((ext_vector_type(8))) short   s16x8;
typedef __attribute__((ext_vector_type(4))) float   f32x4;

#define K_DIM   2048
#define K2      4096        // row stride bytes (bf16)
#define N_DIM   8192
#define N4      4194304     // 8192*2048/4

// ---------------- scale reduction ----------------
__global__ void k_abs_part(const float4* __restrict__ w4, float* __restrict__ part) {
    int tid = blockIdx.x * 256 + threadIdx.x;
    float s = 0.f;
    for (int i = tid; i < N4; i += gridDim.x * 256) {
        float4 v = w4[i];
        s += fabsf(v.x) + fabsf(v.y) + fabsf(v.z) + fabsf(v.w);
    }
    for (int off = 32; off > 0; off >>= 1) s += __shfl_down(s, off, 64);
    __shared__ float tmp[4];
    int lane = threadIdx.x & 63, wid = threadIdx.x >> 6;
    if (lane == 0) tmp[wid] = s;
    __syncthreads();
    if (threadIdx.x == 0) part[blockIdx.x] = tmp[0] + tmp[1] + tmp[2] + tmp[3];
}

__global__ void k_abs_final(const float* __restrict__ part, float* __restrict__ scale) {
    float s = part[threadIdx.x] + part[threadIdx.x + 256] +
              part[threadIdx.x + 512] + part[threadIdx.x + 768];
    for (int off = 32; off > 0; off >>= 1) s += __shfl_down(s, off, 64);
    __shared__ float tmp[4];
    int lane = threadIdx.x & 63, wid = threadIdx.x >> 6;
    if (lane == 0) tmp[wid] = s;
    __syncthreads();
    if (threadIdx.x == 0) scale[0] = (tmp[0] + tmp[1] + tmp[2] + tmp[3]) / 16777216.0f + 1e-8f;
}

// ---------------- fused W-quant + X-convert ----------------
__device__ __forceinline__ uint32_t f2b(float f) {
    uint32_t u = __builtin_bit_cast(uint32_t, f);
    return (u + 0x7FFFu + ((u >> 16) & 1u)) >> 16;  // RNE
}

__global__ void k_prep(const float4* __restrict__ w4, const float4* __restrict__ x4,
                       const float* __restrict__ scale_p,
                       uint2* __restrict__ wq, uint2* __restrict__ xb) {
    int tid = (blockIdx.x & 2047) * 256 + threadIdx.x;
    if (blockIdx.x < 2048) {
        const float sc = *scale_p;
        for (int i = tid; i < N4; i += 2048 * 256) {
            float4 v = w4[i];
            float q0 = rintf(v.x / sc), q1 = rintf(v.y / sc);
            float q2 = rintf(v.z / sc), q3 = rintf(v.w / sc);
            uint32_t b0 = (q0 == 0.f) ? 0u : (q0 > 0.f ? 0x3F80u : 0xBF80u);
            uint32_t b1 = (q1 == 0.f) ? 0u : (q1 > 0.f ? 0x3F80u : 0xBF80u);
            uint32_t b2 = (q2 == 0.f) ? 0u : (q2 > 0.f ? 0x3F80u : 0xBF80u);
            uint32_t b3 = (q3 == 0.f) ? 0u : (q3 > 0.f ? 0x3F80u : 0xBF80u);
            uint2 o; o.x = b0 | (b1 << 16); o.y = b2 | (b3 << 16);
            wq[i] = o;
        }
    } else {
        for (int i = tid; i < N4; i += 2048 * 256) {
            float4 v = x4[i];
            uint2 o;
            o.x = f2b(v.x) | (f2b(v.y) << 16);
            o.y = f2b(v.z) | (f2b(v.w) << 16);
            xb[i] = o;
        }
    }
}

// ---------------- GEMM ----------------
__device__ __forceinline__ void mfma16(f32x4& c, s16x8 a, s16x8 b) {
    asm("v_mfma_f32_16x16x32_bf16 %0, %1, %2, %0" : "+v"(c) : "v"(a), "v"(b));
}
__device__ __forceinline__ void load_lds16(const void* g, void* l) {
    __builtin_amdgcn_global_load_lds(
        (const __attribute__((address_space(1))) uint32_t*)g,
        (__attribute__((address_space(3))) uint32_t*)l, 16, 0, 0);
}

#define SCHED0 __builtin_amdgcn_sched_barrier(0)
#define SBAR do { SCHED0; __builtin_amdgcn_s_barrier(); SCHED0; } while (0)
#define WAIT_VM(N) do { asm volatile("s_waitcnt vmcnt(" #N ")" ::: "memory"); SCHED0; } while (0)

// LDS byte map (128 KiB): buf0.A=0, buf0.B=32768, buf1.A=65536, buf1.B=98304
#define C0 0
#define C1 65536

__global__ __launch_bounds__(512, 2) void k_gemm(
    const unsigned short* __restrict__ Xb,
    const unsigned short* __restrict__ Wb,
    const float* __restrict__ scale_p,
    float* __restrict__ out)
{
    extern __shared__ uint8_t smem[];
    const int tid  = threadIdx.x;
    const int lane = tid & 63;
    const int wid  = tid >> 6;
    const int wr   = wid >> 2;          // 0..1
    const int wc   = wid & 3;           // 0..3

    // 4x8 supertiled XCD mapping (bijective: inverse l = (col>>3)*32 +
    // (row&3)*8 + (col&7), xcd = row>>2).
    const int bid = blockIdx.x;
    const int xcd = bid & 7;
    const int l   = bid >> 3;
    const int tileRow = xcd * 4 + ((l >> 3) & 3);   // 0..31
    const int tileCol = (l >> 5) * 8 + (l & 7);     // 0..31

    const uint8_t* gA = (const uint8_t*)Xb + (size_t)tileRow * 256 * K2;
    const uint8_t* gB = (const uint8_t*)Wb + (size_t)tileCol * 256 * K2;

    // staging: thread t covers row srow and srow+64 of a 128-row x 64-K half-region.
    // physical LDS slot c of row r holds global col-slot (c ^ (r&7))  (XOR swizzle).
    const int srow = tid >> 3, sslot = tid & 7;
    const size_t srcOff = (size_t)srow * K2 + (size_t)((sslot ^ (srow & 7)) * 16);
    const uint8_t* gAs = gA + srcOff;
    const uint8_t* gBs = gB + srcOff;
    const int dstOff = tid * 16;

    // LDS read bases (byte offsets); frag m adds m*2048 (16 rows * 128B)
    const int rA = wr * 128 + (lane & 15);
    const int rB = wc * 64  + (lane & 15);
    const int h  = lane >> 4;
    const int pA0 = rA * 128 + (((h    ) ^ (rA & 7)) * 16);
    const int pA1 = rA * 128 + (((4 + h) ^ (rA & 7)) * 16);
    const int pB0 = rB * 128 + (((h    ) ^ (rB & 7)) * 16);
    const int pB1 = rB * 128 + (((4 + h) ^ (rB & 7)) * 16);

    s16x8 a[8][2], b[4][2];
    f32x4 acc[8][4];
    #pragma unroll
    for (int m = 0; m < 8; ++m)
        #pragma unroll
        for (int n = 0; n < 4; ++n) acc[m][n] = (f32x4){0.f, 0.f, 0.f, 0.f};

#define LD8(OFF) (*(const s16x8*)(smem + (OFF)))
#define STAGE(LBASE, GP, BOFF) do { \
    load_lds16((GP) + (BOFF),          smem + (LBASE) + dstOff); \
    load_lds16((GP) + (BOFF) + 262144, smem + (LBASE) + 8192 + dstOff); \
    SCHED0; } while (0)

#define RD_A03(AB) do { _Pragma("unroll") for (int m = 0; m < 4; ++m) { \
    a[m][0] = LD8((AB) + pA0 + m * 2048); a[m][1] = LD8((AB) + pA1 + m * 2048); } } while (0)
#define RD_A47(AB) do { _Pragma("unroll") for (int m = 4; m < 8; ++m) { \
    a[m][0] = LD8((AB) + pA0 + m * 2048); a[m][1] = LD8((AB) + pA1 + m * 2048); } } while (0)
#define RD_B01(AB) do { _Pragma("unroll") for (int n = 0; n < 2; ++n) { \
    b[n][0] = LD8((AB) + 32768 + pB0 + n * 2048); b[n][1] = LD8((AB) + 32768 + pB1 + n * 2048); } } while (0)
#define RD_B23(AB) do { _Pragma("unroll") for (int n = 2; n < 4; ++n) { \
    b[n][0] = LD8((AB) + 32768 + pB0 + n * 2048); b[n][1] = LD8((AB) + 32768 + pB1 + n * 2048); } } while (0)

#define MFMA_Q(MLO, NLO) do { \
    __builtin_amdgcn_s_setprio(1); \
    _Pragma("unroll") for (int kk = 0; kk < 2; ++kk) \
        _Pragma("unroll") for (int m = 0; m < 4; ++m) \
            _Pragma("unroll") for (int n = 0; n < 2; ++n) \
                mfma16(acc[(MLO) + m][(NLO) + n], a[(MLO) + m][kk], b[(NLO) + n][kk]); \
    __builtin_amdgcn_s_setprio(0); \
    SCHED0; } while (0)

    // prologue: stage tiles 0 (C0) and 1 (C1) fully; force tile 0, leave tile
    // 1's 8 loads in flight; preload nothing (ph1 reads a03/b01 same-phase).
    STAGE(C0,         gAs, 0);   STAGE(C0 + 16384, gAs, 524288);
    STAGE(C0 + 32768, gBs, 0);   STAGE(C0 + 49152, gBs, 524288);
    STAGE(C1,         gAs, 128); STAGE(C1 + 16384, gAs, 524288 + 128);
    STAGE(C1 + 32768, gBs, 128); STAGE(C1 + 49152, gBs, 524288 + 128);
    WAIT_VM(8);
    SBAR;

    #pragma unroll 1
    for (int i = 0; i < 15; ++i) {
        const int kb1 = (2 * i + 1) * 128;   // T+1
        const int kb2 = kb1 + 128;           // T+2
        const int kb3 = kb1 + 256;           // T+3
        // ---- even tile T on C0 ----
        // ph1
        STAGE(C1 + 32768, gBs, kb1);
        RD_A03(C0); RD_B01(C0);
        MFMA_Q(0, 0);
        // ph2
        STAGE(C1 + 49152, gBs, 524288 + kb1);
        RD_A47(C0);
        MFMA_Q(4, 0);
        SBAR;                                   // buf0.A dead
        // ph3
        STAGE(C0, gAs, kb2);
        RD_B23(C0);
        MFMA_Q(0, 2);
        // ph4
        STAGE(C0 + 16384, gAs, 524288 + kb2);
        MFMA_Q(4, 2);
        WAIT_VM(4); SBAR;                       // T+1 landed; buf0.B dead
        // ---- odd tile T+1 on C1 ----
        // ph5
        STAGE(C0 + 32768, gBs, kb2);
        RD_A03(C1); RD_B01(C1);
        MFMA_Q(0, 0);
        // ph6
        STAGE(C0 + 49152, gBs, 524288 + kb2);
        RD_A47(C1);
        MFMA_Q(4, 0);
        SBAR;                                   // buf1.A dead
        // ph7
        STAGE(C1, gAs, kb3);
        RD_B23(C1);
        MFMA_Q(0, 2);
        // ph8
        STAGE(C1 + 16384, gAs, 524288 + kb3);
        MFMA_Q(4, 2);
        WAIT_VM(4); SBAR;                       // T+2 landed; buf1.B dead
    }

    // peeled i=15: tiles 30 (C0), 31 (C1); stage only B_31; then drain
    {
        const int kb1 = 31 * 128;
        STAGE(C1 + 32768, gBs, kb1);
        RD_A03(C0); RD_B01(C0);
        MFMA_Q(0, 0);
        STAGE(C1 + 49152, gBs, 524288 + kb1);
        RD_A47(C0);
        MFMA_Q(4, 0);
        SBAR;
        RD_B23(C0);
        MFMA_Q(0, 2);
        MFMA_Q(4, 2);
        WAIT_VM(0); SBAR;                       // all of tile 31 landed
        RD_A03(C1); RD_B01(C1);
        MFMA_Q(0, 0);
        RD_A47(C1);
        MFMA_Q(4, 0);
        RD_B23(C1);
        MFMA_Q(0, 2);
        MFMA_Q(4, 2);
    }

    // epilogue: C[row][col], col=lane&15, row=(lane>>4)*4+j (verified mapping)
    const float sc = *scale_p;
    const int orow0 = tileRow * 256 + wr * 128 + ((lane >> 4) << 2);
    const int ocol0 = tileCol * 256 + wc * 64 + (lane & 15);
    #pragma unroll
    for (int m = 0; m < 8; ++m)
        #pragma unroll
        for (int n = 0; n < 4; ++n)
            #pragma unroll
            for (int j = 0; j < 4; ++j)
                out[(size_t)(orow0 + m * 16 + j) * N_DIM + (ocol0 + n * 16)] = acc[m][n][j] * sc;

#undef LD8
#undef STAGE
#undef RD_A03
#undef RD_A47
#undef RD_B01
#undef RD_B23
#undef MFMA_Q
}

// ---------------- launch ----------------
extern "C" void kernel_launch(void* const* d_in, const int* in_sizes, int n_in,
                              void* d_out, int out_size, void* d_ws, size_t ws_size,
                              hipStream_t stream) {
    const float* x = (const float*)d_in[0];
    const float* w = (const float*)d_in[1];
    float* out = (float*)d_out;
    uint8_t* ws = (uint8_t*)d_ws;

    float* part  = (float*)ws;                       // 1024 floats
    float* scale = (float*)(ws + 4096);              // 1 float
    unsigned short* Xb = (unsigned short*)(ws + 8192);
    unsigned short* Wb = (unsigned short*)(ws + 8192 + 33554432ull);

    (void)hipFuncSetAttribute((const void*)k_gemm,
                              hipFuncAttributeMaxDynamicSharedMemorySize, 131072);

    hipLaunchKernelGGL(k_abs_part, dim3(1024), dim3(256), 0, stream, (const float4*)w, part);
    hipLaunchKernelGGL(k_abs_final, dim3(1), dim3(256), 0, stream, part, scale);
    hipLaunchKernelGGL(k_prep, dim3(4096), dim3(256), 0, stream,
                       (const float4*)w, (const float4*)x, scale, (uint2*)Wb, (uint2*)Xb);
    hipLaunchKernelGGL(k_gemm, dim3(1024), dim3(512), 131072, stream, Xb, Wb, scale, out);
}